// Round 6
// baseline (323.628 us; speedup 1.0000x reference)
//
#include <hip/hip_runtime.h>
#include <math.h>

// Problem constants (match reference)
constexpr int B = 256;
constexpr int T = 16384;
constexpr int K = 3;

// R12: FUSED single kernel. Post-mortem of R7-R11: the scan's phase rate
// (~2 us) was invariant under register-buffering, f64/f32 LDS-DMA, and
// 4-wave shared-stream loading => the panel round-trip itself (50 MB write +
// 147 MB redundant read) and the never-profiled conv kernel (~137 us for
// ~6 us of f64 math) are the real cost. Conv is cheap enough to RECOMPUTE
// inside the scan: x is 16 MB (L2/L3-resident, 9x reuse). One kernel,
// 1024 blocks x 1 wave (4 waves/CU = 1/SIMD), no panel, no barriers,
// no vmcnt bookkeeping. Numerics bit-match R0's proven path: f64 conv
// (same tap order/scales), f64 W = a-0.05, same STEP, >=512-step warm
// (exact from t=0 for c<8).
constexpr int CHUNK = 64;
constexpr int WARM  = 512;

#define XCOMP(v, jj) ( ((jj) & 3) == 0 ? (v).x                          \
                     : ((jj) & 3) == 1 ? (v).y                          \
                     : ((jj) & 3) == 2 ? (v).z : (v).w )

__global__ __launch_bounds__(64, 1) void fused_kernel(
    const float* __restrict__ x,      // [B][1][T]
    const float* __restrict__ w0f,
    const float* __restrict__ w1f,
    const float* __restrict__ w2f,
    float* __restrict__ u_out,        // [B][K][T]
    float* __restrict__ s_out)        // [B][K][T]
{
    // XCD-aware remap: XCD k gets c in [32k, 32k+32) for all bg -> per-XCD
    // x working set ~2.7 MB (fits the 4 MB XCD L2).
    const int phys = blockIdx.x;           // 1024 blocks
    const int xcd  = phys & 7;
    const int slot = phys >> 3;            // 128 slots
    const int c    = xcd * 32 + (slot & 31);   // chunk 0..255
    const int bg   = slot >> 5;                // 0..3
    const int lane = threadIdx.x;
    const int chain = bg * 64 + lane;

    const int t_emit = c * CHUNK;
    const int t_w    = (t_emit >= WARM) ? (t_emit - WARM) : 0;
    const int n_g    = ((t_emit + CHUNK) - t_w) >> 4;  // 16-step groups; even

    const float* xc = x + (size_t)chain * T;

    // Weights in f64 (R0-exact).
    double w0d[8], w1d[16], w2d[32];
#pragma unroll
    for (int i = 0; i < 8; ++i)  w0d[i] = (double)w0f[i];
#pragma unroll
    for (int i = 0; i < 16; ++i) w1d[i] = (double)w1f[i];
#pragma unroll
    for (int i = 0; i < 32; ++i) w2d[i] = (double)w2f[i];

    const double s8  = 1.0 / sqrt(8.0);
    const double s32 = 1.0 / sqrt(32.0);

    // Ring window win[t & 31] = x[chain][t] (f64). Preload t_w-31 .. t_w-1
    // (t_w % 32 == 0, so slot = t mod 32 = s). Zeros for t<0 (exact ref init).
    double win[32];
    win[0] = 0.0;
#pragma unroll
    for (int s = 1; s < 32; ++s) {
        const int t = t_w - 32 + s;
        win[s] = (t >= 0) ? (double)xc[t] : 0.0;
    }

    // x park ring: 2 groups (32 t) of lookahead, ping-pong pA/pB.
    float4 pA[4], pB[4];
#pragma unroll
    for (int q = 0; q < 4; ++q) pA[q] = *(const float4*)(xc + t_w + 4 * q);
#pragma unroll
    for (int q = 0; q < 4; ++q) pB[q] = *(const float4*)(xc + t_w + 16 + 4 * q);

    // Store-transpose stages (R10-proven full-line store pattern). 25 KB.
    __shared__ float4 ustage[12 * 65];
    __shared__ float4 sstage[12 * 65];

    double m0 = -1.0, m1 = -1.0, m2 = -1.0;    // v=0 -> m=-1 exactly

#define STEP(W0, W1, W2, O0, O1, O2) do {                               \
    const double M0 = fma(0.95, m0, (W0));                              \
    const double M1 = fma(0.95, m1, (W1));                              \
    const double M2 = fma(0.95, m2, (W2));                              \
    const bool c01 = (M0 >= M1);                                        \
    const bool c02 = (M0 >= M2);                                        \
    const bool c12 = (M1 >= M2);                                        \
    const bool f0  = (M0 >= 0.0);                                       \
    const bool f1  = (M1 >= 0.0);                                       \
    const bool f2  = (M2 >= 0.0);                                       \
    const bool s0 = c01 & c02 & f0;          /* first-index argmax */   \
    const bool s1 = (!c01) & c12 & f1;                                  \
    const bool s2 = (!c02) & (!c12) & f2;                               \
    m0 = s0 ? M0 - 1.0 : M0;                                            \
    m1 = s1 ? M1 - 1.0 : M1;                                            \
    m2 = s2 ? M2 - 1.0 : M2;                                            \
    (O0) = s0 ? 1.0f : 0.0f;                                            \
    (O1) = s1 ? 1.0f : 0.0f;                                            \
    (O2) = s2 ? 1.0f : 0.0f;                                            \
} while (0)

// One fused conv+LIF step at t = t_w + 16*g + j; TPAR = 16*(g&1) keeps all
// ring indices compile-time after unroll. Same taps/order/scales as R0.
#define CSTEP(j, TPAR, PC) do {                                               \
    const float _xf = XCOMP((PC)[(j) >> 2], j);                               \
    win[((TPAR) + (j)) & 31] = (double)_xf;                                   \
    double a0 = 0.0, a1 = 0.0, a2 = 0.0;                                      \
    _Pragma("unroll")                                                         \
    for (int i = 0; i < 8; ++i)                                               \
        a0 = fma(w0d[i], win[((TPAR) + (j) + 25 + i) & 31], a0);              \
    _Pragma("unroll")                                                         \
    for (int i = 0; i < 16; ++i)                                              \
        a1 = fma(w1d[i], win[((TPAR) + (j) + 17 + i) & 31], a1);              \
    _Pragma("unroll")                                                         \
    for (int i = 0; i < 32; ++i)                                              \
        a2 = fma(w2d[i], win[((TPAR) + (j) + 1 + i) & 31], a2);               \
    a0 *= s8; a1 *= 0.25; a2 *= s32;                                          \
    fr0[j] = (float)a0; fr1[j] = (float)a1; fr2[j] = (float)a2;               \
    STEP(a0 - 0.05, a1 - 0.05, a2 - 0.05, sp0[j], sp1[j], sp2[j]);            \
} while (0)

// Emit one 16-t group (u and s) via LDS transpose: 4-lane groups write full
// 64 B lines (R10-proven). Single wave -> no barriers, just lgkm drain.
#define EMIT(g) do {                                                          \
    _Pragma("unroll")                                                         \
    for (int _q = 0; _q < 4; ++_q) {                                          \
        ustage[(0 * 4 + _q) * 65 + lane] = ((float4*)fr0)[_q];                \
        ustage[(1 * 4 + _q) * 65 + lane] = ((float4*)fr1)[_q];                \
        ustage[(2 * 4 + _q) * 65 + lane] = ((float4*)fr2)[_q];                \
        sstage[(0 * 4 + _q) * 65 + lane] = ((float4*)sp0)[_q];                \
        sstage[(1 * 4 + _q) * 65 + lane] = ((float4*)sp1)[_q];                \
        sstage[(2 * 4 + _q) * 65 + lane] = ((float4*)sp2)[_q];                \
    }                                                                         \
    asm volatile("s_waitcnt lgkmcnt(0)" ::: "memory");                        \
    __builtin_amdgcn_sched_barrier(0);                                        \
    const int _t = t_w + (g) * 16;                                            \
    _Pragma("unroll")                                                         \
    for (int _k = 0; _k < 3; ++_k) {                                          \
        _Pragma("unroll")                                                     \
        for (int _q = 0; _q < 4; ++_q) {                                      \
            const int _row = _q * 16 + (lane >> 2);                           \
            const float4 _vu = ustage[(_k * 4 + (lane & 3)) * 65 + _row];     \
            const float4 _vs = sstage[(_k * 4 + (lane & 3)) * 65 + _row];     \
            const size_t _off = (size_t)(bg * 64 + _row) * (3 * T)            \
                              + (size_t)_k * T + _t + (lane & 3) * 4;         \
            *(float4*)(u_out + _off) = _vu;                                   \
            *(float4*)(s_out + _off) = _vs;                                   \
        }                                                                     \
    }                                                                         \
} while (0)

// One 16-step group: compute (consumes PC), then reload PC for group g+2
// (after last consume; ~16-step lookahead hides L2 latency), then emit if
// in the last 4 groups. All branches block-uniform.
#define GROUP(g, TPAR, PC) do {                                               \
    if ((g) < n_g) {                                                          \
        float fr0[16], fr1[16], fr2[16];                                      \
        float sp0[16], sp1[16], sp2[16];                                      \
        _Pragma("unroll")                                                     \
        for (int _j = 0; _j < 16; ++_j) CSTEP(_j, TPAR, PC);                  \
        if ((g) + 2 < n_g) {                                                  \
            const float* _pb = xc + t_w + ((g) + 2) * 16;                     \
            _Pragma("unroll")                                                 \
            for (int _q = 0; _q < 4; ++_q)                                    \
                (PC)[_q] = *(const float4*)(_pb + 4 * _q);                    \
            __builtin_amdgcn_sched_barrier(0);                                \
        }                                                                     \
        if ((g) >= n_g - 4) EMIT(g);                                          \
    }                                                                         \
} while (0)

    for (int gp = 0; gp < n_g; gp += 2) {
        GROUP(gp,     0,  pA);
        GROUP(gp + 1, 16, pB);
    }

#undef GROUP
#undef EMIT
#undef CSTEP
#undef STEP
}

// ---------------------------------------------------------------------------
extern "C" void kernel_launch(void* const* d_in, const int* in_sizes, int n_in,
                              void* d_out, int out_size, void* d_ws, size_t ws_size,
                              hipStream_t stream)
{
    const float* x  = (const float*)d_in[0];
    const float* w0 = (const float*)d_in[1];
    const float* w1 = (const float*)d_in[2];
    const float* w2 = (const float*)d_in[3];
    // d_in[4] = y (unused by the reference outputs)

    float* out   = (float*)d_out;
    float* u_out = out;                        // [B][K][T]
    float* s_out = out + (size_t)B * K * T;    // [B][K][T]
    (void)d_ws; (void)ws_size;                 // no intermediate needed anymore

    fused_kernel<<<(B / 64) * (T / CHUNK), 64, 0, stream>>>(
        x, w0, w1, w2, u_out, s_out);
}

// Round 8
// 249.202 us; speedup vs baseline: 1.2987x; 1.2987x over previous
//
#include <hip/hip_runtime.h>
#include <math.h>

// Problem constants (match reference)
constexpr int B = 256;
constexpr int T = 16384;
constexpr int K = 3;

// Speculative chunking: emit 256 steps after 512-step warm-up (proven R5/R6).
constexpr int CHUNK = 256;
constexpr int WARM  = 512;

// Conv tiling: 64 chains x 128 timesteps per block, 4 waves x 32 t each.
constexpr int CBT = 128;
constexpr int CWT = 32;

// R14 = R13 with the compile fix only: __builtin_nontemporal_store rejects
// HIP_vector_type float4; store through clang's native ext-vector alias
// (same 16 B layout, bit-identical).
// R13 rationale (base = R4/217us, best known):
//  1. conv u_out via per-wave LDS half-transpose (lane-adjacent 32B segments
//     instead of 64-line/instr scatter; R2->R4 proved conv is store-bound).
//  2. conv u_out stores NON-TEMPORAL (u never re-read; stop evicting panel).
//  3. scan s_out stores NON-TEMPORAL (same).
// Goal: panel stays L3-resident (scan FETCH 71.5 MB of a 50 MB panel today).

typedef float vfloat4 __attribute__((ext_vector_type(4)));

__device__ __forceinline__ void nt_store4(float* dst, float4 v) {
    vfloat4 nv;
    nv.x = v.x; nv.y = v.y; nv.z = v.z; nv.w = v.w;
    __builtin_nontemporal_store(nv, (vfloat4*)dst);
}

// w32 panel layout [T/16][4 bg][12 q][64 lane] x 16B (float4):
// float4 q of lane i = stream floats (4q..4q+3) of chain (bg*64+i), stream
// ordered (t_local 0..15) x (ch 0..2). Lane-coalesced on both sides.

// ---------------------------------------------------------------------------
// Conv: causal k=8/16/32 in f64 (same tap order / fma / scale as R2-R10).
// ---------------------------------------------------------------------------
__global__ __launch_bounds__(256, 2) void conv_kernel(
    const float* __restrict__ x,
    const float* __restrict__ w0f,
    const float* __restrict__ w1f,
    const float* __restrict__ w2f,
    float*  __restrict__ u_out,   // [B][K][T] f32
    float*  __restrict__ w32)     // panel layout above
{
    const int blk = blockIdx.x;            // 512 blocks
    const int bgi = blk >> 7;              // 4 b-tiles
    const int t0  = (blk & 127) * CBT;     // 128 t-tiles
    const int b0  = bgi * 64;
    const int tid = threadIdx.x;

    __shared__ float sx[64][164];          // cols t0-32 .. t0+127, +4 pad
    // per-wave u-transpose stage: 6 slabs x 65 float4 (8-t half-tiles).
    // LDS total: 41984 + 4*6240 = 66944 B -> still 2 blocks/CU.
    __shared__ float4 ustg[4][6 * 65];

    for (int k = tid; k < 64 * 40; k += 256) {
        const int r  = k / 40;
        const int c4 = k - r * 40;
        const int g  = t0 - 32 + 4 * c4;
        float4 v = make_float4(0.f, 0.f, 0.f, 0.f);
        if (g >= 0) v = *(const float4*)(x + (size_t)(b0 + r) * T + g);
        *(float4*)&sx[r][4 * c4] = v;
    }
    __syncthreads();

    const int lane    = tid & 63;
    const int w       = tid >> 6;
    const int t_start = t0 + CWT * w;
    float4* stg = ustg[w];

    double w0d[8], w1d[16], w2d[32];
#pragma unroll
    for (int i = 0; i < 8; ++i)  w0d[i] = (double)w0f[i];
#pragma unroll
    for (int i = 0; i < 16; ++i) w1d[i] = (double)w1f[i];
#pragma unroll
    for (int i = 0; i < 32; ++i) w2d[i] = (double)w2f[i];

    // ring window: win[t & 31] = x[chain][t]
    double win[32];
#pragma unroll
    for (int k = 1; k < 32; ++k) win[k] = (double)sx[lane][CWT * w + k];

    const double s8  = 1.0 / sqrt(8.0);
    const double s32 = 1.0 / sqrt(32.0);

    float fr0[16], fr1[16], fr2[16];
    float4 pf;                              // panel float4 batcher

// Put stream value v at slot D; flush the float4 when last component lands.
// Store instr: 64 lanes x 16 B contiguous = 1 KB coalesced. Panel stores
// stay CACHED (scan re-reads them).
#define PPUT(v, D) do {                                                       \
    const float _pv = (v);                                                    \
    if (((D) & 3) == 0) pf.x = _pv;                                           \
    else if (((D) & 3) == 1) pf.y = _pv;                                      \
    else if (((D) & 3) == 2) pf.z = _pv;                                      \
    else {                                                                    \
        pf.w = _pv;                                                           \
        *(float4*)(wq + ((D) >> 2) * 256) = pf;                               \
    }                                                                         \
} while (0)

#pragma unroll
    for (int j = 0; j < CWT; ++j) {
        win[j & 31] = (double)sx[lane][CWT * w + 32 + j];   // push x[t]
        double a0 = 0.0, a1 = 0.0, a2 = 0.0;
#pragma unroll
        for (int i = 0; i < 8; ++i)  a0 = fma(w0d[i], win[(j + 25 + i) & 31], a0);
#pragma unroll
        for (int i = 0; i < 16; ++i) a1 = fma(w1d[i], win[(j + 17 + i) & 31], a1);
#pragma unroll
        for (int i = 0; i < 32; ++i) a2 = fma(w2d[i], win[(j + 1 + i) & 31], a2);
        a0 *= s8; a1 *= 0.25; a2 *= s32;

        const int t = t_start + j;
        float* wq = w32 + ((size_t)(t >> 4) * 4 + bgi) * 3072 + lane * 4;
        const int D0 = (j & 15) * 3;                        // t&15 == j&15
        PPUT((float)(a0 - 0.05), D0);
        PPUT((float)(a1 - 0.05), D0 + 1);
        PPUT((float)(a2 - 0.05), D0 + 2);

        fr0[j & 15] = (float)a0; fr1[j & 15] = (float)a1; fr2[j & 15] = (float)a2;
        if ((j & 15) == 15) {
            // u emit via per-wave LDS transpose, two 8-t halves; stores are
            // lane-pair-contiguous 32 B segments, NON-TEMPORAL (u never
            // re-read; keep it out of L3 so the panel stays resident).
            const int t_base = t_start + (j & ~15);
#pragma unroll
            for (int h = 0; h < 2; ++h) {
#pragma unroll
                for (int qh = 0; qh < 2; ++qh) {
                    stg[(0 * 2 + qh) * 65 + lane] = ((float4*)fr0)[2 * h + qh];
                    stg[(1 * 2 + qh) * 65 + lane] = ((float4*)fr1)[2 * h + qh];
                    stg[(2 * 2 + qh) * 65 + lane] = ((float4*)fr2)[2 * h + qh];
                }
                asm volatile("s_waitcnt lgkmcnt(0)" ::: "memory");
                __builtin_amdgcn_sched_barrier(0);
#pragma unroll
                for (int k = 0; k < 3; ++k) {
#pragma unroll
                    for (int i2 = 0; i2 < 2; ++i2) {
                        const float4 v =
                            stg[(k * 2 + (lane & 1)) * 65 + i2 * 32 + (lane >> 1)];
                        float* dst = u_out
                            + (size_t)(b0 + i2 * 32 + (lane >> 1)) * (3 * T)
                            + (size_t)k * T + t_base + 8 * h + 4 * (lane & 1);
                        nt_store4(dst, v);
                    }
                }
                // WAR: reads of this half must land before next half rewrites
                asm volatile("s_waitcnt lgkmcnt(0)" ::: "memory");
                __builtin_amdgcn_sched_barrier(0);
            }
        }
    }
#undef PPUT
}

// ---------------------------------------------------------------------------
// Scan: speculative chunked LIF-WTA, one (chain, chunk) per lane, 1 wave/CU.
// f64 state, f32 W. LDS-DMA triple buffer + LDS-transposed full-line s_out
// stores (both R4-proven). Only change: s_out stores are NON-TEMPORAL.
// ---------------------------------------------------------------------------
__global__ __launch_bounds__(64, 1) void scan_kernel(
    const float* __restrict__ w32,
    float* __restrict__ s_out)        // [B][K][T] f32
{
    // blockIdx -> XCD is round-robin (bid & 7 on 8 XCDs); cluster c-ranges.
    const int phys = blockIdx.x;
    const int xcd  = phys & 7;
    const int slot = phys >> 3;            // 32 blocks per XCD
    const int c    = 8 * xcd + (slot & 7); // contiguous chunk range per XCD
    const int bg   = slot >> 3;
    const int lane = threadIdx.x;

    const int t_emit = c * CHUNK;
    const int t_w    = (t_emit >= WARM) ? (t_emit - WARM) : 0;
    const int warm_g = (t_emit - t_w) >> 4;     // 0, 16, or 32
    const int n_g    = warm_g + (CHUNK >> 4);   // 16, 32, or 48
    const int tw16   = t_w >> 4;

    // 3 slabs x 12 KB (one 16-step group each) = 36 KB LDS ring.
    __shared__ float4 lbuf[3 * 768];
    // store-transpose stage: 12 slabs (k*4+q) x 64 chains, +1 float4 pad.
    __shared__ float4 sstage[12 * 65];

    double m0 = -1.0, m1 = -1.0, m2 = -1.0;     // v=0 -> m=-1 exactly

// Counted-vmcnt wait. N is a guaranteed lower bound on the number of vmem
// ops issued after the awaited slab's last DMA load.
#define WAITN(N) do {                                                   \
    asm volatile("s_waitcnt vmcnt(" #N ")" ::: "memory");               \
    __builtin_amdgcn_sched_barrier(0);                                  \
} while (0)

// DMA one 12 KB group into slab s: 12 instrs, each 64 lanes x 16 B.
#define LOADDMA(s, gg) do {                                                   \
    const float4* _src = (const float4*)(w32 +                                \
        ((size_t)(tw16 + (gg)) * 4 + bg) * 3072) + lane;                      \
    _Pragma("unroll")                                                         \
    for (int _q = 0; _q < 12; ++_q)                                           \
        __builtin_amdgcn_global_load_lds(                                     \
            (const __attribute__((address_space(1))) void*)(const void*)      \
                (_src + (size_t)_q * 64),                                     \
            (__attribute__((address_space(3))) void*)(void*)                  \
                (&lbuf[(s) * 768 + _q * 64]),                                 \
            16, 0, 0);                                                        \
} while (0)

#define STEP(W0, W1, W2, O0, O1, O2) do {                               \
    const double M0 = fma(0.95, m0, (W0));                              \
    const double M1 = fma(0.95, m1, (W1));                              \
    const double M2 = fma(0.95, m2, (W2));                              \
    const bool c01 = (M0 >= M1);                                        \
    const bool c02 = (M0 >= M2);                                        \
    const bool c12 = (M1 >= M2);                                        \
    const bool f0  = (M0 >= 0.0);                                       \
    const bool f1  = (M1 >= 0.0);                                       \
    const bool f2  = (M2 >= 0.0);                                       \
    const bool s0 = c01 & c02 & f0;          /* first-index argmax */   \
    const bool s1 = (!c01) & c12 & f1;                                  \
    const bool s2 = (!c02) & (!c12) & f2;                               \
    m0 = s0 ? M0 - 1.0 : M0;                                            \
    m1 = s1 ? M1 - 1.0 : M1;                                            \
    m2 = s2 ? M2 - 1.0 : M2;                                            \
    (O0) = s0 ? 1.0f : 0.0f;                                            \
    (O1) = s1 ? 1.0f : 0.0f;                                            \
    (O2) = s2 ? 1.0f : 0.0f;                                            \
} while (0)

// Compile-time component select keeps _rf in registers after full unroll.
#define GETW(d) ( ((d) & 3) == 0 ? _rf[(d) >> 2].x                      \
                : ((d) & 3) == 1 ? _rf[(d) >> 2].y                      \
                : ((d) & 3) == 2 ? _rf[(d) >> 2].z                      \
                :                  _rf[(d) >> 2].w )

// Per-phase wait counts (R8-proven):
//   warm steady / first emit: 24 | p==warm_g+1: 36 | emit steady: 48
//   p == n_g-2: 36 | p == n_g-1: 24
#define BODY(s, pp) do {                                                      \
    if ((pp) < n_g) {                                                         \
        if ((pp) == n_g - 1)            WAITN(24);                            \
        else if ((pp) == n_g - 2)       WAITN(36);                            \
        else if ((pp) >= warm_g + 2)    WAITN(48);                            \
        else if ((pp) == warm_g + 1)    WAITN(36);                            \
        else                            WAITN(24);                            \
        const float4* _lp = lbuf + (s) * 768 + lane;                          \
        float4 _rf[12];                                                       \
        _Pragma("unroll")                                                     \
        for (int _q = 0; _q < 12; ++_q) _rf[_q] = _lp[(size_t)_q * 64];       \
        float sp0[16], sp1[16], sp2[16];                                      \
        _Pragma("unroll")                                                     \
        for (int _j = 0; _j < 16; ++_j) {                                     \
            const int _d0 = 3 * _j;                                           \
            const double _W0 = (double)GETW(_d0);                             \
            const double _W1 = (double)GETW(_d0 + 1);                         \
            const double _W2 = (double)GETW(_d0 + 2);                         \
            STEP(_W0, _W1, _W2, sp0[_j], sp1[_j], sp2[_j]);                   \
        }                                                                     \
        if ((pp) + 3 < n_g) LOADDMA(s, (pp) + 3);                             \
        if ((pp) >= warm_g) {                                                 \
            _Pragma("unroll")                                                 \
            for (int _q = 0; _q < 4; ++_q) {                                  \
                sstage[(0 * 4 + _q) * 65 + lane] = ((float4*)sp0)[_q];        \
                sstage[(1 * 4 + _q) * 65 + lane] = ((float4*)sp1)[_q];        \
                sstage[(2 * 4 + _q) * 65 + lane] = ((float4*)sp2)[_q];        \
            }                                                                 \
            asm volatile("s_waitcnt lgkmcnt(0)" ::: "memory");                \
            __builtin_amdgcn_sched_barrier(0);                                \
            const int _t = t_w + (pp) * 16;                                   \
            _Pragma("unroll")                                                 \
            for (int _k = 0; _k < 3; ++_k) {                                  \
                _Pragma("unroll")                                             \
                for (int _g = 0; _g < 4; ++_g) {                              \
                    const float4 _v =                                         \
                        sstage[(_k * 4 + (lane & 3)) * 65 + _g * 16 + (lane >> 2)]; \
                    float* _dst = s_out                                       \
                        + (size_t)(bg * 64 + _g * 16 + (lane >> 2)) * (3 * T) \
                        + (size_t)_k * T + _t + (lane & 3) * 4;               \
                    nt_store4(_dst, _v);                                      \
                }                                                             \
            }                                                                 \
        }                                                                     \
    }                                                                         \
} while (0)

    LOADDMA(0, 0);
    LOADDMA(1, 1);
    LOADDMA(2, 2);
    for (int p = 0; p < n_g; p += 3) {
        BODY(0, p);
        BODY(1, p + 1);
        BODY(2, p + 2);
    }

#undef BODY
#undef GETW
#undef STEP
#undef LOADDMA
#undef WAITN
}

// ---------------------------------------------------------------------------
extern "C" void kernel_launch(void* const* d_in, const int* in_sizes, int n_in,
                              void* d_out, int out_size, void* d_ws, size_t ws_size,
                              hipStream_t stream)
{
    const float* x  = (const float*)d_in[0];
    const float* w0 = (const float*)d_in[1];
    const float* w1 = (const float*)d_in[2];
    const float* w2 = (const float*)d_in[3];
    // d_in[4] = y (unused by the reference outputs)

    float* out   = (float*)d_out;
    float* u_out = out;                        // [B][K][T]
    float* s_out = out + (size_t)B * K * T;    // [B][K][T]

    float* w32 = (float*)d_ws;                 // 50.3 MB f32 panel (ws >= 100 MB)

    conv_kernel<<<(B / 64) * (T / CBT), 256, 0, stream>>>(x, w0, w1, w2, u_out, w32);
    scan_kernel<<<B, 64, 0, stream>>>(w32, s_out);
}

// Round 9
// 227.266 us; speedup vs baseline: 1.4240x; 1.0965x over previous
//
#include <hip/hip_runtime.h>
#include <math.h>

// Problem constants (match reference)
constexpr int B = 256;
constexpr int T = 16384;
constexpr int K = 3;

// Speculative chunking: emit 256 steps after 512-step warm-up (proven R5/R6).
constexpr int CHUNK = 256;
constexpr int WARM  = 512;

// Conv tiling: 64 chains x 128 timesteps per block, 4 waves x 32 t each.
constexpr int CBT = 128;
constexpr int CWT = 32;

// R15 (base = R4/217us): PANEL ELIMINATED. The w32 panel was u-0.05 in a
// swizzled layout: 50 MB of redundant writes in conv + swizzled-store
// machinery. The scan's global_load_lds takes PER-LANE global addresses
// (m173), so it can gather straight from u_out: instr (k,tq) loads lane=
// chain's floats [k*T + t0+4tq .. +4) -- 4 instrs share each 64 B line,
// L2 coalesces, same 192 lines/group as the panel path. W = u - 0.05 is
// computed in f64 in the scan (noise class == the f32-panel rounding,
// proven passing 4x). Wait counts CORRECTED (R8's NT experiment proved
// waits were retiring stores): steady emit is 60 newer ops, not 48 --
// no wait ever drains a store now. All stores plain cached (NT reverted:
// +22us regression, FETCH unchanged).

// ---------------------------------------------------------------------------
// Conv: causal k=8/16/32 in f64 (same tap order / fma / scale as R2-R10).
// u_out stores = R4's proven direct float4 path. Panel gone.
// ---------------------------------------------------------------------------
__global__ __launch_bounds__(256, 2) void conv_kernel(
    const float* __restrict__ x,
    const float* __restrict__ w0f,
    const float* __restrict__ w1f,
    const float* __restrict__ w2f,
    float*  __restrict__ u_out)   // [B][K][T] f32
{
    const int blk = blockIdx.x;            // 512 blocks
    const int bgi = blk >> 7;              // 4 b-tiles
    const int t0  = (blk & 127) * CBT;     // 128 t-tiles
    const int b0  = bgi * 64;
    const int tid = threadIdx.x;

    __shared__ float sx[64][164];          // cols t0-32 .. t0+127, +4 pad
    for (int k = tid; k < 64 * 40; k += 256) {
        const int r  = k / 40;
        const int c4 = k - r * 40;
        const int g  = t0 - 32 + 4 * c4;
        float4 v = make_float4(0.f, 0.f, 0.f, 0.f);
        if (g >= 0) v = *(const float4*)(x + (size_t)(b0 + r) * T + g);
        *(float4*)&sx[r][4 * c4] = v;
    }
    __syncthreads();

    const int lane    = tid & 63;
    const int w       = tid >> 6;
    const int t_start = t0 + CWT * w;

    double w0d[8], w1d[16], w2d[32];
#pragma unroll
    for (int i = 0; i < 8; ++i)  w0d[i] = (double)w0f[i];
#pragma unroll
    for (int i = 0; i < 16; ++i) w1d[i] = (double)w1f[i];
#pragma unroll
    for (int i = 0; i < 32; ++i) w2d[i] = (double)w2f[i];

    // ring window: win[t & 31] = x[chain][t]
    double win[32];
#pragma unroll
    for (int k = 1; k < 32; ++k) win[k] = (double)sx[lane][CWT * w + k];

    const double s8  = 1.0 / sqrt(8.0);
    const double s32 = 1.0 / sqrt(32.0);

    float fr0[16], fr1[16], fr2[16];
    float* uf = u_out + (size_t)(b0 + lane) * (3 * T);

#pragma unroll
    for (int j = 0; j < CWT; ++j) {
        win[j & 31] = (double)sx[lane][CWT * w + 32 + j];   // push x[t]
        double a0 = 0.0, a1 = 0.0, a2 = 0.0;
#pragma unroll
        for (int i = 0; i < 8; ++i)  a0 = fma(w0d[i], win[(j + 25 + i) & 31], a0);
#pragma unroll
        for (int i = 0; i < 16; ++i) a1 = fma(w1d[i], win[(j + 17 + i) & 31], a1);
#pragma unroll
        for (int i = 0; i < 32; ++i) a2 = fma(w2d[i], win[(j + 1 + i) & 31], a2);
        a0 *= s8; a1 *= 0.25; a2 *= s32;

        fr0[j & 15] = (float)a0; fr1[j & 15] = (float)a1; fr2[j & 15] = (float)a2;
        if ((j & 15) == 15) {
            float* d = uf + t_start + (j & ~15);
#pragma unroll
            for (int q = 0; q < 4; ++q) {
                *(float4*)(d + 4 * q)         = ((float4*)fr0)[q];
                *(float4*)(d + T + 4 * q)     = ((float4*)fr1)[q];
                *(float4*)(d + 2 * T + 4 * q) = ((float4*)fr2)[q];
            }
        }
    }
}

// ---------------------------------------------------------------------------
// Scan: speculative chunked LIF-WTA, one (chain, chunk) per lane, 1 wave/CU.
// f64 state; W gathered straight from u_out via per-lane global_load_lds.
// LDS slab layout [q=k*4+tq][lane] float4: instr q loads lane=chain's
// channel-k floats t0+4*tq..+3. Triple buffer + corrected counted vmcnt +
// LDS-transposed full-line s_out stores (R4-proven).
// ---------------------------------------------------------------------------
__global__ __launch_bounds__(64, 1) void scan_kernel(
    const float* __restrict__ u_out,
    float* __restrict__ s_out)        // [B][K][T] f32
{
    // blockIdx -> XCD is round-robin (bid & 7 on 8 XCDs); cluster c-ranges
    // (adjacent chunks share 66% of their u window in the XCD L2).
    const int phys = blockIdx.x;
    const int xcd  = phys & 7;
    const int slot = phys >> 3;            // 32 blocks per XCD
    const int c    = 8 * xcd + (slot & 7); // contiguous chunk range per XCD
    const int bg   = slot >> 3;
    const int lane = threadIdx.x;

    const int t_emit = c * CHUNK;
    const int t_w    = (t_emit >= WARM) ? (t_emit - WARM) : 0;
    const int warm_g = (t_emit - t_w) >> 4;     // 0, 16, or 32
    const int n_g    = warm_g + (CHUNK >> 4);   // 16, 32, or 48
    const int tw16   = t_w >> 4;

    // 3 slabs x 12 KB (one 16-step group each) = 36 KB LDS ring.
    __shared__ float4 lbuf[3 * 768];
    // store-transpose stage: 12 slabs (k*4+q) x 64 chains, +1 float4 pad.
    __shared__ float4 sstage[12 * 65];

    double m0 = -1.0, m1 = -1.0, m2 = -1.0;     // v=0 -> m=-1 exactly

    // per-lane (=chain) base into u_out
    const float* ub = u_out + (size_t)(bg * 64 + lane) * (3 * T);

// Counted-vmcnt wait. N = exact count of vmem ops issued after the awaited
// group's last DMA load (derivation below) -- waits never retire stores.
#define WAITN(N) do {                                                   \
    asm volatile("s_waitcnt vmcnt(" #N ")" ::: "memory");               \
    __builtin_amdgcn_sched_barrier(0);                                  \
} while (0)

// DMA one group (16 t x 3 ch) into slab s: 12 instrs, 64 lanes x 16 B each.
// Global source is PER-LANE (ub + k*T + t); LDS dest is uniform + lane*16.
// 4 instrs (tq=0..3) share each (chain,k) 64 B line -> L2 coalesces.
#define LOADDMA(s, gg) do {                                                   \
    const float* _sb = ub + (size_t)(tw16 + (gg)) * 16;                       \
    _Pragma("unroll")                                                         \
    for (int _k = 0; _k < 3; ++_k)                                            \
        _Pragma("unroll")                                                     \
        for (int _tq = 0; _tq < 4; ++_tq)                                     \
            __builtin_amdgcn_global_load_lds(                                 \
                (const __attribute__((address_space(1))) void*)(const void*)  \
                    (_sb + (size_t)_k * T + 4 * _tq),                         \
                (__attribute__((address_space(3))) void*)(void*)              \
                    (&lbuf[(s) * 768 + (_k * 4 + _tq) * 64]),                 \
                16, 0, 0);                                                    \
} while (0)

#define STEP(W0, W1, W2, O0, O1, O2) do {                               \
    const double M0 = fma(0.95, m0, (W0));                              \
    const double M1 = fma(0.95, m1, (W1));                              \
    const double M2 = fma(0.95, m2, (W2));                              \
    const bool c01 = (M0 >= M1);                                        \
    const bool c02 = (M0 >= M2);                                        \
    const bool c12 = (M1 >= M2);                                        \
    const bool f0  = (M0 >= 0.0);                                       \
    const bool f1  = (M1 >= 0.0);                                       \
    const bool f2  = (M2 >= 0.0);                                       \
    const bool s0 = c01 & c02 & f0;          /* first-index argmax */   \
    const bool s1 = (!c01) & c12 & f1;                                  \
    const bool s2 = (!c02) & (!c12) & f2;                               \
    m0 = s0 ? M0 - 1.0 : M0;                                            \
    m1 = s1 ? M1 - 1.0 : M1;                                            \
    m2 = s2 ? M2 - 1.0 : M2;                                            \
    (O0) = s0 ? 1.0f : 0.0f;                                            \
    (O1) = s1 ? 1.0f : 0.0f;                                            \
    (O2) = s2 ? 1.0f : 0.0f;                                            \
} while (0)

// Compile-time component select keeps _rf in registers after full unroll.
// Channel k of step j lives in _rf[k*4 + (j>>2)] component (j&3).
#define GETC(q, cc) ( (cc) == 0 ? _rf[q].x                              \
                    : (cc) == 1 ? _rf[q].y                              \
                    : (cc) == 2 ? _rf[q].z : _rf[q].w )
#define GETWK(k, j) ((double)GETC((k) * 4 + ((j) >> 2), (j) & 3))

// Wait-count derivation (issue order, phase p: WAIT -> ds_read -> compute ->
// LOADDMA(p+3) -> stores(p); L(p) issued at phase p-3 BEFORE stores(p-3)).
// newer(L(p)) = stores(p-3) + L(p+1) + stores(p-2) + L(p+2) + stores(p-1)
//   warm steady (no stores yet):            24
//   p == warm_g+1:                          36
//   p == warm_g+2:                          48
//   p >= warm_g+3 (steady emit):            60   <- was 48: drained a store
//   p == n_g-2 (L(p+2) never issued):       48
//   p == n_g-1 (L(p+1),L(p+2) never):       36
#define BODY(s, pp) do {                                                      \
    if ((pp) < n_g) {                                                         \
        if ((pp) == n_g - 1)            WAITN(36);                            \
        else if ((pp) == n_g - 2)       WAITN(48);                            \
        else if ((pp) >= warm_g + 3)    WAITN(60);                            \
        else if ((pp) == warm_g + 2)    WAITN(48);                            \
        else if ((pp) == warm_g + 1)    WAITN(36);                            \
        else                            WAITN(24);                            \
        const float4* _lp = lbuf + (s) * 768 + lane;                          \
        float4 _rf[12];                                                       \
        _Pragma("unroll")                                                     \
        for (int _q = 0; _q < 12; ++_q) _rf[_q] = _lp[(size_t)_q * 64];       \
        float sp0[16], sp1[16], sp2[16];                                      \
        _Pragma("unroll")                                                     \
        for (int _j = 0; _j < 16; ++_j) {                                     \
            STEP(GETWK(0, _j) - 0.05, GETWK(1, _j) - 0.05,                    \
                 GETWK(2, _j) - 0.05, sp0[_j], sp1[_j], sp2[_j]);             \
        }                                                                     \
        if ((pp) + 3 < n_g) LOADDMA(s, (pp) + 3);                             \
        if ((pp) >= warm_g) {                                                 \
            _Pragma("unroll")                                                 \
            for (int _q = 0; _q < 4; ++_q) {                                  \
                sstage[(0 * 4 + _q) * 65 + lane] = ((float4*)sp0)[_q];        \
                sstage[(1 * 4 + _q) * 65 + lane] = ((float4*)sp1)[_q];        \
                sstage[(2 * 4 + _q) * 65 + lane] = ((float4*)sp2)[_q];        \
            }                                                                 \
            asm volatile("s_waitcnt lgkmcnt(0)" ::: "memory");                \
            __builtin_amdgcn_sched_barrier(0);                                \
            const int _t = t_w + (pp) * 16;                                   \
            _Pragma("unroll")                                                 \
            for (int _k = 0; _k < 3; ++_k) {                                  \
                _Pragma("unroll")                                             \
                for (int _g = 0; _g < 4; ++_g) {                              \
                    const float4 _v =                                         \
                        sstage[(_k * 4 + (lane & 3)) * 65 + _g * 16 + (lane >> 2)]; \
                    float* _dst = s_out                                       \
                        + (size_t)(bg * 64 + _g * 16 + (lane >> 2)) * (3 * T) \
                        + (size_t)_k * T + _t + (lane & 3) * 4;               \
                    *(float4*)_dst = _v;                                      \
                }                                                             \
            }                                                                 \
        }                                                                     \
    }                                                                         \
} while (0)

    LOADDMA(0, 0);
    LOADDMA(1, 1);
    LOADDMA(2, 2);
    for (int p = 0; p < n_g; p += 3) {
        BODY(0, p);
        BODY(1, p + 1);
        BODY(2, p + 2);
    }

#undef BODY
#undef GETWK
#undef GETC
#undef STEP
#undef LOADDMA
#undef WAITN
}

// ---------------------------------------------------------------------------
extern "C" void kernel_launch(void* const* d_in, const int* in_sizes, int n_in,
                              void* d_out, int out_size, void* d_ws, size_t ws_size,
                              hipStream_t stream)
{
    const float* x  = (const float*)d_in[0];
    const float* w0 = (const float*)d_in[1];
    const float* w1 = (const float*)d_in[2];
    const float* w2 = (const float*)d_in[3];
    // d_in[4] = y (unused by the reference outputs)

    float* out   = (float*)d_out;
    float* u_out = out;                        // [B][K][T]
    float* s_out = out + (size_t)B * K * T;    // [B][K][T]
    (void)d_ws; (void)ws_size;                 // panel eliminated

    conv_kernel<<<(B / 64) * (T / CBT), 256, 0, stream>>>(x, w0, w1, w2, u_out);
    scan_kernel<<<B, 64, 0, stream>>>(u_out, s_out);
}

// Round 10
// 208.029 us; speedup vs baseline: 1.5557x; 1.0925x over previous
//
#include <hip/hip_runtime.h>
#include <math.h>

// Problem constants (match reference)
constexpr int B = 256;
constexpr int T = 16384;
constexpr int K = 3;

// R16: base = R4 (217us, best proven: panel + LDS-DMA triple buffer +
// transposed full-line s_out stores). Two changes:
//  1. CHUNK 256 -> 128: 512 INDEPENDENT 1-wave scan blocks = 2 blocks/CU.
//     The scan's ~7 GB/s/wave load rate was invariant across five load
//     schemes at 1 block/CU; this is the clean occupancy probe (R5's 4-wave
//     variant was confounded by lockstep barriers + redundant compute).
//     Cost: logical bytes 147 -> 245 MB (warm amortization); win if
//     concurrency scales: scan ~80 -> ~60-68 us.
//  2. Corrected vmcnt wait table (R8's NT experiment proved waits were
//     retiring stores; steady emit = 60 newer ops, not 48). Verified
//     parametrically for warm_g in {0,8,16,24,32}, n_g in {8..40}.
// Conv reverted to R4 exact (R9 proved conv is NOT write-volume-bound;
// panel restored, direct-u gather dropped: it cost +9 us on the scan).
constexpr int CHUNK = 128;
constexpr int WARM  = 512;

// Conv tiling: 64 chains x 128 timesteps per block, 4 waves x 32 t each.
constexpr int CBT = 128;
constexpr int CWT = 32;

// w32 panel layout [T/16][4 bg][12 q][64 lane] x 16B (float4):
// float4 q of lane i = stream floats (4q..4q+3) of chain (bg*64+i), stream
// ordered (t_local 0..15) x (ch 0..2). Lane-coalesced on both sides.

// ---------------------------------------------------------------------------
// Conv: causal k=8/16/32 in f64 (same tap order / fma / scale as R2-R10).
// R4-exact: PPUT register-batched panel stores + direct float4 u stores.
// ---------------------------------------------------------------------------
__global__ __launch_bounds__(256, 2) void conv_kernel(
    const float* __restrict__ x,
    const float* __restrict__ w0f,
    const float* __restrict__ w1f,
    const float* __restrict__ w2f,
    float*  __restrict__ u_out,   // [B][K][T] f32
    float*  __restrict__ w32)     // panel layout above
{
    const int blk = blockIdx.x;            // 512 blocks
    const int bgi = blk >> 7;              // 4 b-tiles
    const int t0  = (blk & 127) * CBT;     // 128 t-tiles
    const int b0  = bgi * 64;
    const int tid = threadIdx.x;

    __shared__ float sx[64][164];          // cols t0-32 .. t0+127, +4 pad
    for (int k = tid; k < 64 * 40; k += 256) {
        const int r  = k / 40;
        const int c4 = k - r * 40;
        const int g  = t0 - 32 + 4 * c4;
        float4 v = make_float4(0.f, 0.f, 0.f, 0.f);
        if (g >= 0) v = *(const float4*)(x + (size_t)(b0 + r) * T + g);
        *(float4*)&sx[r][4 * c4] = v;
    }
    __syncthreads();

    const int lane    = tid & 63;
    const int w       = tid >> 6;
    const int t_start = t0 + CWT * w;

    double w0d[8], w1d[16], w2d[32];
#pragma unroll
    for (int i = 0; i < 8; ++i)  w0d[i] = (double)w0f[i];
#pragma unroll
    for (int i = 0; i < 16; ++i) w1d[i] = (double)w1f[i];
#pragma unroll
    for (int i = 0; i < 32; ++i) w2d[i] = (double)w2f[i];

    // ring window: win[t & 31] = x[chain][t]
    double win[32];
#pragma unroll
    for (int k = 1; k < 32; ++k) win[k] = (double)sx[lane][CWT * w + k];

    const double s8  = 1.0 / sqrt(8.0);
    const double s32 = 1.0 / sqrt(32.0);

    float fr0[16], fr1[16], fr2[16];
    float4 pf;                              // panel float4 batcher
    float* uf = u_out + (size_t)(b0 + lane) * (3 * T);

// Put stream value v at slot D; flush the float4 when last component lands.
// Store instr: 64 lanes x 16 B contiguous = 1 KB coalesced.
#define PPUT(v, D) do {                                                       \
    const float _pv = (v);                                                    \
    if (((D) & 3) == 0) pf.x = _pv;                                           \
    else if (((D) & 3) == 1) pf.y = _pv;                                      \
    else if (((D) & 3) == 2) pf.z = _pv;                                      \
    else {                                                                    \
        pf.w = _pv;                                                           \
        *(float4*)(wq + ((D) >> 2) * 256) = pf;                               \
    }                                                                         \
} while (0)

#pragma unroll
    for (int j = 0; j < CWT; ++j) {
        win[j & 31] = (double)sx[lane][CWT * w + 32 + j];   // push x[t]
        double a0 = 0.0, a1 = 0.0, a2 = 0.0;
#pragma unroll
        for (int i = 0; i < 8; ++i)  a0 = fma(w0d[i], win[(j + 25 + i) & 31], a0);
#pragma unroll
        for (int i = 0; i < 16; ++i) a1 = fma(w1d[i], win[(j + 17 + i) & 31], a1);
#pragma unroll
        for (int i = 0; i < 32; ++i) a2 = fma(w2d[i], win[(j + 1 + i) & 31], a2);
        a0 *= s8; a1 *= 0.25; a2 *= s32;

        const int t = t_start + j;
        float* wq = w32 + ((size_t)(t >> 4) * 4 + bgi) * 3072 + lane * 4;
        const int D0 = (j & 15) * 3;                        // t&15 == j&15
        PPUT((float)(a0 - 0.05), D0);
        PPUT((float)(a1 - 0.05), D0 + 1);
        PPUT((float)(a2 - 0.05), D0 + 2);

        fr0[j & 15] = (float)a0; fr1[j & 15] = (float)a1; fr2[j & 15] = (float)a2;
        if ((j & 15) == 15) {
            float* d = uf + t_start + (j & ~15);
#pragma unroll
            for (int q = 0; q < 4; ++q) {
                *(float4*)(d + 4 * q)         = ((float4*)fr0)[q];
                *(float4*)(d + T + 4 * q)     = ((float4*)fr1)[q];
                *(float4*)(d + 2 * T + 4 * q) = ((float4*)fr2)[q];
            }
        }
    }
#undef PPUT
}

// ---------------------------------------------------------------------------
// Scan: speculative chunked LIF-WTA, one (chain, chunk) per lane, now at
// CHUNK=128 -> 512 independent 1-wave blocks (2 blocks/CU). f64 state,
// f32 W. LDS-DMA triple buffer + corrected counted vmcnt + LDS-transposed
// full-line s_out stores.
// ---------------------------------------------------------------------------
__global__ __launch_bounds__(64, 1) void scan_kernel(
    const float* __restrict__ w32,
    float* __restrict__ s_out)        // [B][K][T] f32
{
    // XCD remap: 512 blocks = 8 XCD x 64 slots; XCD k gets c in [16k,16k+16)
    // for each bg (adjacent chunks share 32/40 groups in the XCD L2).
    const int phys = blockIdx.x;
    const int xcd  = phys & 7;
    const int slot = phys >> 3;             // 0..63
    const int c    = xcd * 16 + (slot & 15);    // 0..127
    const int bg   = slot >> 4;                 // 0..3
    const int lane = threadIdx.x;

    const int t_emit = c * CHUNK;
    const int t_w    = (t_emit >= WARM) ? (t_emit - WARM) : 0;
    const int warm_g = (t_emit - t_w) >> 4;     // 0, 8, 16, 24, or 32
    const int n_g    = warm_g + (CHUNK >> 4);   // 8 .. 40
    const int tw16   = t_w >> 4;

    // 3 slabs x 12 KB (one 16-step group each) = 36 KB LDS ring.
    __shared__ float4 lbuf[3 * 768];
    // store-transpose stage: 12 slabs (k*4+q) x 64 chains, +1 float4 pad.
    __shared__ float4 sstage[12 * 65];

    double m0 = -1.0, m1 = -1.0, m2 = -1.0;     // v=0 -> m=-1 exactly

// Counted-vmcnt wait. N = exact count of vmem ops issued after the awaited
// group's last DMA load -- waits never retire stores (R15-corrected table).
#define WAITN(N) do {                                                   \
    asm volatile("s_waitcnt vmcnt(" #N ")" ::: "memory");               \
    __builtin_amdgcn_sched_barrier(0);                                  \
} while (0)

// DMA one 12 KB group into slab s: 12 instrs, each 64 lanes x 16 B,
// contiguous 1 KB per instruction (panel layout).
#define LOADDMA(s, gg) do {                                                   \
    const float4* _src = (const float4*)(w32 +                                \
        ((size_t)(tw16 + (gg)) * 4 + bg) * 3072) + lane;                      \
    _Pragma("unroll")                                                         \
    for (int _q = 0; _q < 12; ++_q)                                           \
        __builtin_amdgcn_global_load_lds(                                     \
            (const __attribute__((address_space(1))) void*)(const void*)      \
                (_src + (size_t)_q * 64),                                     \
            (__attribute__((address_space(3))) void*)(void*)                  \
                (&lbuf[(s) * 768 + _q * 64]),                                 \
            16, 0, 0);                                                        \
} while (0)

#define STEP(W0, W1, W2, O0, O1, O2) do {                               \
    const double M0 = fma(0.95, m0, (W0));                              \
    const double M1 = fma(0.95, m1, (W1));                              \
    const double M2 = fma(0.95, m2, (W2));                              \
    const bool c01 = (M0 >= M1);                                        \
    const bool c02 = (M0 >= M2);                                        \
    const bool c12 = (M1 >= M2);                                        \
    const bool f0  = (M0 >= 0.0);                                       \
    const bool f1  = (M1 >= 0.0);                                       \
    const bool f2  = (M2 >= 0.0);                                       \
    const bool s0 = c01 & c02 & f0;          /* first-index argmax */   \
    const bool s1 = (!c01) & c12 & f1;                                  \
    const bool s2 = (!c02) & (!c12) & f2;                               \
    m0 = s0 ? M0 - 1.0 : M0;                                            \
    m1 = s1 ? M1 - 1.0 : M1;                                            \
    m2 = s2 ? M2 - 1.0 : M2;                                            \
    (O0) = s0 ? 1.0f : 0.0f;                                            \
    (O1) = s1 ? 1.0f : 0.0f;                                            \
    (O2) = s2 ? 1.0f : 0.0f;                                            \
} while (0)

// Compile-time component select keeps _rf in registers after full unroll.
#define GETW(d) ( ((d) & 3) == 0 ? _rf[(d) >> 2].x                      \
                : ((d) & 3) == 1 ? _rf[(d) >> 2].y                      \
                : ((d) & 3) == 2 ? _rf[(d) >> 2].z                      \
                :                  _rf[(d) >> 2].w )

// Wait-count derivation (issue order, phase p: WAIT -> ds_read -> compute ->
// LOADDMA(p+3) -> stores(p); L(p) issued at phase p-3 before stores(p-3)).
// newer(L(p)) = stores(p-3) + L(p+1) + stores(p-2) + L(p+2) + stores(p-1):
//   warm steady (no stores yet):            24
//   p == warm_g+1:                          36
//   p == warm_g+2:                          48
//   p >= warm_g+3 (steady emit):            60
//   p == n_g-2 (L(p+2) never issued):       48
//   p == n_g-1 (L(p+1),L(p+2) never):       36
// Verified parametrically for warm_g in {0,8,16,24,32} incl. n_g=8 tail.
#define BODY(s, pp) do {                                                      \
    if ((pp) < n_g) {                                                         \
        if ((pp) == n_g - 1)            WAITN(36);                            \
        else if ((pp) == n_g - 2)       WAITN(48);                            \
        else if ((pp) >= warm_g + 3)    WAITN(60);                            \
        else if ((pp) == warm_g + 2)    WAITN(48);                            \
        else if ((pp) == warm_g + 1)    WAITN(36);                            \
        else                            WAITN(24);                            \
        const float4* _lp = lbuf + (s) * 768 + lane;                          \
        float4 _rf[12];                                                       \
        _Pragma("unroll")                                                     \
        for (int _q = 0; _q < 12; ++_q) _rf[_q] = _lp[(size_t)_q * 64];       \
        float sp0[16], sp1[16], sp2[16];                                      \
        _Pragma("unroll")                                                     \
        for (int _j = 0; _j < 16; ++_j) {                                     \
            const int _d0 = 3 * _j;                                           \
            const double _W0 = (double)GETW(_d0);                             \
            const double _W1 = (double)GETW(_d0 + 1);                         \
            const double _W2 = (double)GETW(_d0 + 2);                         \
            STEP(_W0, _W1, _W2, sp0[_j], sp1[_j], sp2[_j]);                   \
        }                                                                     \
        if ((pp) + 3 < n_g) LOADDMA(s, (pp) + 3);                             \
        if ((pp) >= warm_g) {                                                 \
            _Pragma("unroll")                                                 \
            for (int _q = 0; _q < 4; ++_q) {                                  \
                sstage[(0 * 4 + _q) * 65 + lane] = ((float4*)sp0)[_q];        \
                sstage[(1 * 4 + _q) * 65 + lane] = ((float4*)sp1)[_q];        \
                sstage[(2 * 4 + _q) * 65 + lane] = ((float4*)sp2)[_q];        \
            }                                                                 \
            asm volatile("s_waitcnt lgkmcnt(0)" ::: "memory");                \
            __builtin_amdgcn_sched_barrier(0);                                \
            const int _t = t_w + (pp) * 16;                                   \
            _Pragma("unroll")                                                 \
            for (int _k = 0; _k < 3; ++_k) {                                  \
                _Pragma("unroll")                                             \
                for (int _g = 0; _g < 4; ++_g) {                              \
                    const float4 _v =                                         \
                        sstage[(_k * 4 + (lane & 3)) * 65 + _g * 16 + (lane >> 2)]; \
                    float* _dst = s_out                                       \
                        + (size_t)(bg * 64 + _g * 16 + (lane >> 2)) * (3 * T) \
                        + (size_t)_k * T + _t + (lane & 3) * 4;               \
                    *(float4*)_dst = _v;                                      \
                }                                                             \
            }                                                                 \
        }                                                                     \
    }                                                                         \
} while (0)

    LOADDMA(0, 0);
    LOADDMA(1, 1);
    LOADDMA(2, 2);
    for (int p = 0; p < 48; p += 3) {
        if (p >= n_g) break;
        BODY(0, p);
        BODY(1, p + 1);
        BODY(2, p + 2);
    }

#undef BODY
#undef GETW
#undef STEP
#undef LOADDMA
#undef WAITN
}

// ---------------------------------------------------------------------------
extern "C" void kernel_launch(void* const* d_in, const int* in_sizes, int n_in,
                              void* d_out, int out_size, void* d_ws, size_t ws_size,
                              hipStream_t stream)
{
    const float* x  = (const float*)d_in[0];
    const float* w0 = (const float*)d_in[1];
    const float* w1 = (const float*)d_in[2];
    const float* w2 = (const float*)d_in[3];
    // d_in[4] = y (unused by the reference outputs)

    float* out   = (float*)d_out;
    float* u_out = out;                        // [B][K][T]
    float* s_out = out + (size_t)B * K * T;    // [B][K][T]

    float* w32 = (float*)d_ws;                 // 50.3 MB f32 panel (ws >= 100 MB)

    conv_kernel<<<(B / 64) * (T / CBT), 256, 0, stream>>>(x, w0, w1, w2, u_out, w32);
    scan_kernel<<<(B / 64) * (T / CHUNK), 64, 0, stream>>>(w32, s_out);
}